// Round 1
// baseline (424.692 us; speedup 1.0000x reference)
//
#include <hip/hip_runtime.h>

// Izhikevich neuron scan: B=16, T=1000, D=4096, fp32.
// One thread per neuron (B*D = 65536 threads), sequential loop over T.
// Layout: in/out are [B, T, D]; neuron (b,d) strides by D per timestep,
// so at fixed t the 64 lanes of a wave touch consecutive d -> fully coalesced.
//
// NOTE ON NUMERICS: spike threshold makes the system chaotic (local Lyapunov
// ~2.5x/step near v=30). Must match XLA's rounding bit-exactly: strict
// left-to-right fp32, NO fma contraction (#pragma clang fp contract(off)).

constexpr int T_STEPS = 1000;
constexpr int D_DIM   = 4096;
constexpr int U       = 20;   // prefetch depth; divides T_STEPS

__global__ __launch_bounds__(256)
void izhikevich_kernel(const float* __restrict__ I, float* __restrict__ out, int BD) {
    #pragma clang fp contract(off)
    int n = blockIdx.x * 256 + threadIdx.x;
    if (n >= BD) return;
    int b = n / D_DIM;
    int d = n % D_DIM;
    const size_t base = (size_t)b * T_STEPS * D_DIM + d;
    const float* ip = I + base;
    float*       op = out + base;

    float v = -65.0f;
    float u = 0.2f * -65.0f;   // B_P * V_INIT = -13.0f exactly

    for (int tb = 0; tb < T_STEPS; tb += U) {
        // Stage U independent loads (keeps ~20 loads in flight per wave;
        // only 1 wave/SIMD chip-wide so latency hiding is pure ILP).
        float ibuf[U];
        #pragma unroll
        for (int j = 0; j < U; ++j)
            ibuf[j] = ip[(size_t)(tb + j) * D_DIM];

        #pragma unroll
        for (int j = 0; j < U; ++j) {
            float i_t = ibuf[j];
            // dv = 0.04*v*v + 5.0*v + 140.0 - u + i_t   (exact Python order)
            float dv = 0.04f * v * v + 5.0f * v + 140.0f - u + i_t;
            v = v + 0.2f * dv;                    // v += DT*dv
            float du = 0.02f * (0.2f * v - u);    // A*(B_P*v - u), new v
            u = u + 0.2f * du;                    // u += DT*du
            bool s = (v >= 30.0f);
            op[(size_t)(tb + j) * D_DIM] = s ? 1.0f : 0.0f;
            if (s) { v = -65.0f; u = u + 6.0f; }  // reset: C_P / u + D_P
        }
    }
}

extern "C" void kernel_launch(void* const* d_in, const int* in_sizes, int n_in,
                              void* d_out, int out_size, void* d_ws, size_t ws_size,
                              hipStream_t stream) {
    const float* I  = (const float*)d_in[0];
    float*      out = (float*)d_out;
    int total = in_sizes[0];            // B*T*D = 65,536,000
    int BD    = total / T_STEPS;        // 65,536 neurons
    int block = 256;
    int grid  = (BD + block - 1) / block;
    izhikevich_kernel<<<grid, block, 0, stream>>>(I, out, BD);
}

// Round 2
// 415.157 us; speedup vs baseline: 1.0230x; 1.0230x over previous
//
#include <hip/hip_runtime.h>

// Izhikevich neuron scan: B=16, T=1000, D=4096, fp32.
// One thread per neuron (65,536 threads = 1024 waves = 1 wave/SIMD chip-wide:
// max parallelism; the t-recurrence is strictly sequential). Memory-bound:
// 524 MB compulsory traffic -> ~83 us floor @ 6.3 TB/s.
//
// R1 showed ~140 us kernel (60% of BW): bursty load pattern left HBM idle
// during every compute phase. Fix: register ping-pong double-buffer so one
// full U-batch of loads (20 KB/CU > 9.2 KB latency*BW product) is ALWAYS in
// flight while the other is consumed. Nontemporal loads/stores: streams are
// never re-read, keep them out of L2.
//
// NUMERICS: chaotic near v=30 -> must match XLA bit-exactly: strict
// left-to-right fp32, no FMA contraction. Verified absmax=0 in R1.

constexpr int T_STEPS = 1000;
constexpr int D_DIM   = 4096;
constexpr int U       = 20;   // batch depth; T_STEPS % (2*U) == 0

__global__ __launch_bounds__(256)
void izhikevich_kernel(const float* __restrict__ I, float* __restrict__ out, int BD) {
    #pragma clang fp contract(off)
    int n = blockIdx.x * 256 + threadIdx.x;
    if (n >= BD) return;
    int b = n / D_DIM;
    int d = n % D_DIM;
    const size_t base = (size_t)b * T_STEPS * D_DIM + d;
    const float* ip = I + base;
    float*       op = out + base;

    float v = -65.0f;
    float u = 0.2f * -65.0f;   // B_P * V_INIT

    float buf0[U], buf1[U];

    // Preload batch 0.
    #pragma unroll
    for (int j = 0; j < U; ++j)
        buf0[j] = __builtin_nontemporal_load(ip + (size_t)j * D_DIM);

    // One timestep; strict evaluation order (matches JAX/XLA bit-exactly).
    auto step = [&](float i_t, float* o) {
        float dv = 0.04f * v * v + 5.0f * v + 140.0f - u + i_t;
        v = v + 0.2f * dv;
        float du = 0.02f * (0.2f * v - u);
        u = u + 0.2f * du;
        bool s = (v >= 30.0f);
        __builtin_nontemporal_store(s ? 1.0f : 0.0f, o);
        if (s) { v = -65.0f; u = u + 6.0f; }
    };

    for (int tb = 0; tb < T_STEPS; tb += 2 * U) {
        // Prefetch batch tb+U while consuming buf0 (always valid: tb+2U <= T).
        #pragma unroll
        for (int j = 0; j < U; ++j)
            buf1[j] = __builtin_nontemporal_load(ip + (size_t)(tb + U + j) * D_DIM);

        #pragma unroll
        for (int j = 0; j < U; ++j)
            step(buf0[j], op + (size_t)(tb + j) * D_DIM);

        // Prefetch batch tb+2U while consuming buf1 (skip on last iteration).
        if (tb + 2 * U < T_STEPS) {
            #pragma unroll
            for (int j = 0; j < U; ++j)
                buf0[j] = __builtin_nontemporal_load(ip + (size_t)(tb + 2 * U + j) * D_DIM);
        }

        #pragma unroll
        for (int j = 0; j < U; ++j)
            step(buf1[j], op + (size_t)(tb + U + j) * D_DIM);
    }
}

extern "C" void kernel_launch(void* const* d_in, const int* in_sizes, int n_in,
                              void* d_out, int out_size, void* d_ws, size_t ws_size,
                              hipStream_t stream) {
    const float* I  = (const float*)d_in[0];
    float*      out = (float*)d_out;
    int total = in_sizes[0];            // B*T*D
    int BD    = total / T_STEPS;        // 65,536 neurons
    int block = 256;
    int grid  = (BD + block - 1) / block;
    izhikevich_kernel<<<grid, block, 0, stream>>>(I, out, BD);
}